// Round 14
// baseline (406.478 us; speedup 1.0000x reference)
//
#include <hip/hip_runtime.h>

typedef unsigned short ushort_t;
typedef unsigned int uint_t;
typedef __attribute__((ext_vector_type(8))) __bf16 bf16x8;
typedef __attribute__((ext_vector_type(4))) float f32x4;
typedef __attribute__((ext_vector_type(4))) uint_t uint4v;

#define NN 160000
#define DD 128
#define EE 600000
#define RR 8
#define NRR (NN * RR)          // 1,280,000 (rel,dst) pairs
#define WTOT 376832            // total bf16 weight elements

__device__ __forceinline__ ushort_t f2b(float f) {
  uint_t u = __float_as_uint(f);
  u = u + 0x7fffu + ((u >> 16) & 1u);   // round-nearest-even
  return (ushort_t)(u >> 16);
}
__device__ __forceinline__ float b2f(ushort_t u) {
  return __uint_as_float(((uint_t)u) << 16);
}

__device__ __forceinline__ void gload_lds16(const ushort_t* g, ushort_t* l) {
  __builtin_amdgcn_global_load_lds(
      (const __attribute__((address_space(1))) void*)g,
      (__attribute__((address_space(3))) void*)l, 16, 0, 0);
}

// ---------------- merged weight convert+transpose for all 9 matrices ----------------
// m 0..4 (projection weights): plain transposed [128][K].
// m 5..8 (root1, root2, W1, W2): pre-swizzled LDS image: dst[n*128 + ((kc^(n&7))*8 + kr)],
// k = kc*8+kr  — so rgcn_conv can global_load_lds the image linearly.
struct WSrcs { const float* s[9]; };

__global__ void wconv_all_kernel(WSrcs srcs, ushort_t* __restrict__ wbuf) {
  int i = blockIdx.x * blockDim.x + threadIdx.x;
  if (i >= WTOT) return;
  int m, start, K;
  if      (i < 32768)  { m = 0; start = 0;      K = 256; }
  else if (i < 49152)  { m = 1; start = 32768;  K = 128; }
  else if (i < 65536)  { m = 2; start = 49152;  K = 128; }
  else if (i < 73728)  { m = 3; start = 65536;  K = 64;  }
  else if (i < 81920)  { m = 4; start = 73728;  K = 64;  }
  else if (i < 98304)  { m = 5; start = 81920;  K = 128; }
  else if (i < 114688) { m = 6; start = 98304;  K = 128; }
  else if (i < 245760) { m = 7; start = 114688; K = 128; }
  else                 { m = 8; start = 245760; K = 128; }
  int local = i - start;
  int per = K * 128;
  int mat = local / per, rem = local - mat * per;
  int k = rem >> 7, n = rem & 127;
  ushort_t v = f2b(srcs.s[m][local]);
  if (m < 5) {
    wbuf[start + mat * per + n * K + k] = v;
  } else {
    int kc = k >> 3, kr = k & 7;
    int slot = kc ^ (n & 7);
    wbuf[start + mat * per + n * 128 + slot * 8 + kr] = v;
  }
}

// ---------------- projection GEMM: C[M x 128](bf16) = A[M x K](f32) @ WT[128 x K](bf16) ----------------
__global__ __launch_bounds__(256, 2) void gemm_proj(
    const float* __restrict__ Ain, const ushort_t* __restrict__ WT,
    const float* __restrict__ bias, ushort_t* __restrict__ Cout, int M, int K) {
  __shared__ ushort_t As[128 * 128];
  __shared__ ushort_t Ws[128 * 128];
  const int tid = threadIdx.x;
  const int bm = blockIdx.x * 128;
  const int wave = tid >> 6, lane = tid & 63;
  const int lr = lane & 15;
  const int lg = lane >> 4;

  f32x4 acc[2][8];
#pragma unroll
  for (int mt = 0; mt < 2; ++mt)
#pragma unroll
    for (int nt = 0; nt < 8; ++nt) acc[mt][nt] = {0.f, 0.f, 0.f, 0.f};

  for (int k0 = 0; k0 < K; k0 += 128) {
#pragma unroll
    for (int it = 0; it < 8; ++it) {
      int row = it * 16 + (tid >> 4);
      int c = tid & 15;
      uint4v val = {0, 0, 0, 0};
      int grow = bm + row, gk = k0 + c * 8;
      if (grow < M && gk < K) {
        const float* ap = Ain + (size_t)grow * K + gk;
        float4 v0 = *(const float4*)ap;
        float4 v1 = *(const float4*)(ap + 4);
        val[0] = (uint_t)f2b(v0.x) | ((uint_t)f2b(v0.y) << 16);
        val[1] = (uint_t)f2b(v0.z) | ((uint_t)f2b(v0.w) << 16);
        val[2] = (uint_t)f2b(v1.x) | ((uint_t)f2b(v1.y) << 16);
        val[3] = (uint_t)f2b(v1.z) | ((uint_t)f2b(v1.w) << 16);
      }
      *(uint4v*)&As[row * 128 + ((c ^ (row & 7)) * 8)] = val;
    }
#pragma unroll
    for (int it = 0; it < 8; ++it) {
      int n = it * 16 + (tid >> 4);
      int c = tid & 15;
      uint4v val = {0, 0, 0, 0};
      int gk = k0 + c * 8;
      if (gk < K)
        val = *(const uint4v*)(WT + (size_t)n * K + gk);
      *(uint4v*)&Ws[n * 128 + ((c ^ (n & 7)) * 8)] = val;
    }
    __syncthreads();
#pragma unroll
    for (int ks = 0; ks < 4; ++ks) {
      int chunk = ks * 4 + lg;
      bf16x8 af[2], bfr[8];
#pragma unroll
      for (int mt = 0; mt < 2; ++mt) {
        int row = wave * 32 + mt * 16 + lr;
        af[mt] = *(const bf16x8*)&As[row * 128 + ((chunk ^ (row & 7)) * 8)];
      }
#pragma unroll
      for (int nt = 0; nt < 8; ++nt) {
        int n = nt * 16 + lr;
        bfr[nt] = *(const bf16x8*)&Ws[n * 128 + ((chunk ^ (n & 7)) * 8)];
      }
#pragma unroll
      for (int mt = 0; mt < 2; ++mt)
#pragma unroll
        for (int nt = 0; nt < 8; ++nt)
          acc[mt][nt] = __builtin_amdgcn_mfma_f32_16x16x32_bf16(
              af[mt], bfr[nt], acc[mt][nt], 0, 0, 0);
    }
    __syncthreads();
  }

  float bv[8];
#pragma unroll
  for (int nt = 0; nt < 8; ++nt) bv[nt] = bias[nt * 16 + lr];

#pragma unroll
  for (int mt = 0; mt < 2; ++mt) {
    int rbase = bm + wave * 32 + mt * 16 + lg * 4;
#pragma unroll
    for (int i = 0; i < 4; ++i) {
      int row = rbase + i;
      if (row >= M) continue;
#pragma unroll
      for (int nt = 0; nt < 8; ++nt)
        Cout[(size_t)row * 128 + nt * 16 + lr] = f2b(acc[mt][nt][i] + bv[nt]);
    }
  }
}

// ---------------- pipelined fused RGCN conv (BM=128, 512 threads: 2 M x 4 N waves) ----------------
// out[d] = xin[d]@root + bias + sum_r W_r @ mean_{(r,d)-edges}(xin[src])
// Phases: rels 0..7, then root. Depth-1 pipeline: bounds 3 ahead, srcs 2 ahead, row-vals 1 ahead.
// barrier2 is lgkm-only (raw s_barrier) so in-flight row gathers survive across it.
// (2Mx4N wave grid cuts per-phase LDS fragment reads: 24KB/wave vs 20KB for 64 rows in r13 ->
//  2.0 KB per output row vs 3.25 — the conv was LDS-BW-bound at 4.7GB/conv.)
template <bool RELU_BF>
__global__ __launch_bounds__(512, 4) void rgcn_conv(
    const ushort_t* __restrict__ xin, const int* __restrict__ seg_off,
    const int* __restrict__ sorted_src,
    const ushort_t* __restrict__ WrT,     // 8 x swizzled 128x128 image
    const ushort_t* __restrict__ rootT,   // swizzled 128x128 image
    const float* __restrict__ bias,
    float* __restrict__ fout, ushort_t* __restrict__ bfout) {
  __shared__ ushort_t As[128 * 128];   // 32 KB
  __shared__ ushort_t Ws[128 * 128];   // 32 KB
  const int tid = threadIdx.x;
  const int bm = blockIdx.x * 128;
  const int wave = tid >> 6, lane = tid & 63;
  const int wm = wave & 1;             // M-half (rows wm*64..wm*64+63)
  const int wn = wave >> 1;            // N-quarter (cols wn*32..wn*32+31)
  const int lr = lane & 15, lg = lane >> 4;
  const int grp = tid >> 4;            // 0..31
  const int sl = tid & 15;

  f32x4 acc[4][2];
#pragma unroll
  for (int rt = 0; rt < 4; ++rt)
#pragma unroll
    for (int ct = 0; ct < 2; ++ct) acc[rt][ct] = {0.f, 0.f, 0.f, 0.f};

  // pipeline state (fully unrolled loop -> registers, windowed liveness; 4 rows/group)
  int gsv[8][4], gev[8][4];
  int s0v[8][4], s1v[8][4];
  uint4v f0v[8][4], f1v[8][4];
  uint4v rootv[4];

#define BOUNDS(P)                                                         \
  {                                                                       \
    _Pragma("unroll") for (int q = 0; q < 4; ++q) {                       \
      int g = (P) * NN + bm + q * 32 + grp;                               \
      gsv[P][q] = seg_off[g];                                             \
      gev[P][q] = seg_off[g + 1];                                         \
    }                                                                     \
  }

// unconditional clamped (branch-free, batched) index loads
#define SRCS(P)                                                           \
  {                                                                       \
    _Pragma("unroll") for (int q = 0; q < 4; ++q) {                       \
      int a = gsv[P][q];                                                  \
      int c = gev[P][q] - a;                                              \
      int i0 = (a < EE - 1) ? a : (EE - 1);                               \
      int i1 = (c > 1) ? (a + 1) : i0;                                    \
      s0v[P][q] = sorted_src[i0];                                         \
      s1v[P][q] = sorted_src[i1];                                         \
    }                                                                     \
  }

#define FVLOAD(P)                                                         \
  {                                                                       \
    _Pragma("unroll") for (int q = 0; q < 4; ++q) {                       \
      f0v[P][q] = *(const uint4v*)(xin + (size_t)s0v[P][q] * DD + sl * 8);\
      f1v[P][q] = *(const uint4v*)(xin + (size_t)s1v[P][q] * DD + sl * 8);\
    }                                                                     \
  }

// 8 waves x 4 KB each = 32 KB weight image
#define GLLW(SRC)                                                         \
  {                                                                       \
    const ushort_t* wsrc = (SRC) + (size_t)wave * 2048 + lane * 8;        \
    _Pragma("unroll") for (int i = 0; i < 4; ++i)                         \
      gload_lds16(wsrc + i * 512, &Ws[wave * 2048 + i * 512]);            \
  }

  // ---- prologue ----
  BOUNDS(0); BOUNDS(1); BOUNDS(2);
  GLLW(WrT);
  SRCS(0); SRCS(1);
  FVLOAD(0);
  __builtin_amdgcn_sched_barrier(0);

#pragma unroll
  for (int p = 0; p < 8; ++p) {
    // ---- A-write: means for rel p (consumes f0/f1[p]) ----
#pragma unroll
    for (int q = 0; q < 4; ++q) {
      int row = q * 32 + grp;
      int a = gsv[p][q];
      int c = gev[p][q] - a;
      uint4v o = {0, 0, 0, 0};
      if (c == 1) {
        o = f0v[p][q];                  // mean of one = itself (bit-exact)
      } else if (c == 2) {
        uint4v x0 = f0v[p][q], x1 = f1v[p][q];
#pragma unroll
        for (int j = 0; j < 4; ++j) {
          float e0 = (b2f((ushort_t)(x0[j] & 0xffff)) + b2f((ushort_t)(x1[j] & 0xffff))) * 0.5f;
          float e1 = (b2f((ushort_t)(x0[j] >> 16)) + b2f((ushort_t)(x1[j] >> 16))) * 0.5f;
          o[j] = (uint_t)f2b(e0) | ((uint_t)f2b(e1) << 16);
        }
      } else if (c >= 3) {
        uint4v x0 = f0v[p][q], x1 = f1v[p][q];
        float av[8];
#pragma unroll
        for (int j = 0; j < 4; ++j) {
          av[j * 2]     = b2f((ushort_t)(x0[j] & 0xffff)) + b2f((ushort_t)(x1[j] & 0xffff));
          av[j * 2 + 1] = b2f((ushort_t)(x0[j] >> 16)) + b2f((ushort_t)(x1[j] >> 16));
        }
        for (int i = a + 2; i < a + c; ++i) {
          int s = sorted_src[i];
          uint4v v2 = *(const uint4v*)(xin + (size_t)s * DD + sl * 8);
#pragma unroll
          for (int j = 0; j < 4; ++j) {
            av[j * 2]     += b2f((ushort_t)(v2[j] & 0xffff));
            av[j * 2 + 1] += b2f((ushort_t)(v2[j] >> 16));
          }
        }
        float sc = 1.0f / (float)c;
#pragma unroll
        for (int j = 0; j < 4; ++j)
          o[j] = (uint_t)f2b(av[j * 2] * sc) | ((uint_t)f2b(av[j * 2 + 1] * sc) << 16);
      }
      *(uint4v*)&As[row * 128 + ((sl ^ (row & 7)) * 8)] = o;
    }

    __syncthreads();   // barrier1: A_p + W_p (gll) visible

    // ---- issue next phase's row-value gathers (survive barrier2) ----
    if (p < 7) {
      FVLOAD(p + 1);
    } else {
#pragma unroll
      for (int q = 0; q < 4; ++q)
        rootv[q] = *(const uint4v*)(xin + (size_t)(bm + q * 32 + grp) * DD + sl * 8);
    }
    __builtin_amdgcn_sched_barrier(0);

    // ---- MFMA accumulate for phase p (wave: 64 rows x 32 cols) ----
#pragma unroll
    for (int ks = 0; ks < 4; ++ks) {
      int chunk = ks * 4 + lg;
      bf16x8 af[4], bfr[2];
#pragma unroll
      for (int rt = 0; rt < 4; ++rt) {
        int arow = wm * 64 + rt * 16 + lr;
        af[rt] = *(const bf16x8*)&As[arow * 128 + ((chunk ^ (arow & 7)) * 8)];
      }
#pragma unroll
      for (int ct = 0; ct < 2; ++ct) {
        int n = wn * 32 + ct * 16 + lr;
        bfr[ct] = *(const bf16x8*)&Ws[n * 128 + ((chunk ^ (n & 7)) * 8)];
      }
#pragma unroll
      for (int rt = 0; rt < 4; ++rt)
#pragma unroll
        for (int ct = 0; ct < 2; ++ct)
          acc[rt][ct] = __builtin_amdgcn_mfma_f32_16x16x32_bf16(
              af[rt], bfr[ct], acc[rt][ct], 0, 0, 0);
    }

    // barrier2: lgkm-only (LDS reads done) — does NOT drain the fv gathers
    asm volatile("s_waitcnt lgkmcnt(0)" ::: "memory");
    __builtin_amdgcn_s_barrier();
    __builtin_amdgcn_sched_barrier(0);

    // ---- refill W for next phase; extend index pipeline ----
    if (p < 7) {
      GLLW(WrT + (size_t)(p + 1) * 16384);
    } else {
      GLLW(rootT);
    }
    if (p < 6) { SRCS(p + 2); }
    if (p < 5) { BOUNDS(p + 3); }
    __builtin_amdgcn_sched_barrier(0);
  }

  // ---- phase 8: root ----
#pragma unroll
  for (int q = 0; q < 4; ++q) {
    int row = q * 32 + grp;
    *(uint4v*)&As[row * 128 + ((sl ^ (row & 7)) * 8)] = rootv[q];
  }
  __syncthreads();   // drains root-W gll, A visible
#pragma unroll
  for (int ks = 0; ks < 4; ++ks) {
    int chunk = ks * 4 + lg;
    bf16x8 af[4], bfr[2];
#pragma unroll
    for (int rt = 0; rt < 4; ++rt) {
      int arow = wm * 64 + rt * 16 + lr;
      af[rt] = *(const bf16x8*)&As[arow * 128 + ((chunk ^ (arow & 7)) * 8)];
    }
#pragma unroll
    for (int ct = 0; ct < 2; ++ct) {
      int n = wn * 32 + ct * 16 + lr;
      bfr[ct] = *(const bf16x8*)&Ws[n * 128 + ((chunk ^ (n & 7)) * 8)];
    }
#pragma unroll
    for (int rt = 0; rt < 4; ++rt)
#pragma unroll
      for (int ct = 0; ct < 2; ++ct)
        acc[rt][ct] = __builtin_amdgcn_mfma_f32_16x16x32_bf16(
            af[rt], bfr[ct], acc[rt][ct], 0, 0, 0);
  }

  // ---- epilogue: bias (+relu) and write ----
  float bv[2];
#pragma unroll
  for (int ct = 0; ct < 2; ++ct) bv[ct] = bias[wn * 32 + ct * 16 + lr];

#pragma unroll
  for (int rt = 0; rt < 4; ++rt) {
    int rbase = bm + wm * 64 + rt * 16 + lg * 4;
#pragma unroll
    for (int i = 0; i < 4; ++i) {
      int row = rbase + i;
#pragma unroll
      for (int ct = 0; ct < 2; ++ct) {
        int col = wn * 32 + ct * 16 + lr;
        float v = acc[rt][ct][i] + bv[ct];
        if (RELU_BF)
          bfout[(size_t)row * 128 + col] = f2b(fmaxf(v, 0.f));
        else
          fout[(size_t)row * 128 + col] = v;
      }
    }
  }
#undef BOUNDS
#undef SRCS
#undef FVLOAD
#undef GLLW
}

// ---------------- edge bucketing ----------------
__global__ void count_kernel(const int* __restrict__ dstv, const int* __restrict__ et,
                             int* __restrict__ cnt, int E) {
  int e = blockIdx.x * blockDim.x + threadIdx.x;
  if (e < E) atomicAdd(&cnt[(size_t)et[e] * NN + dstv[e]], 1);
}

__global__ __launch_bounds__(256) void scan1_kernel(const int* __restrict__ in, int* __restrict__ out,
                                                    int* __restrict__ partials, int n) {
  __shared__ int sums[256];
  int tid = threadIdx.x;
  int base = blockIdx.x * 2048 + tid * 8;
  int v[8];
  int s = 0;
#pragma unroll
  for (int i = 0; i < 8; ++i) {
    int idx = base + i;
    int x = (idx < n) ? in[idx] : 0;
    v[i] = s;
    s += x;
  }
  sums[tid] = s;
  __syncthreads();
  for (int off = 1; off < 256; off <<= 1) {
    int t = (tid >= off) ? sums[tid - off] : 0;
    __syncthreads();
    sums[tid] += t;
    __syncthreads();
  }
  int excl = (tid == 0) ? 0 : sums[tid - 1];
  if (tid == 255) partials[blockIdx.x] = sums[255];
#pragma unroll
  for (int i = 0; i < 8; ++i) {
    int idx = base + i;
    if (idx < n) out[idx] = excl + v[i];
  }
}

__global__ __launch_bounds__(256) void scan2_kernel(int* __restrict__ partials, int nb) {
  __shared__ int sums[256];
  int tid = threadIdx.x;
  int per = (nb + 255) / 256;
  int start = tid * per;
  int s = 0;
  for (int i = 0; i < per; ++i) {
    int idx = start + i;
    if (idx < nb) s += partials[idx];
  }
  sums[tid] = s;
  __syncthreads();
  for (int off = 1; off < 256; off <<= 1) {
    int t = (tid >= off) ? sums[tid - off] : 0;
    __syncthreads();
    sums[tid] += t;
    __syncthreads();
  }
  int excl = (tid == 0) ? 0 : sums[tid - 1];
  for (int i = 0; i < per; ++i) {
    int idx = start + i;
    if (idx < nb) {
      int t = partials[idx];
      partials[idx] = excl;
      excl += t;
    }
  }
}

// also writes the sentinel out[n] = EE (out must have n+1 slots)
__global__ void scan3_kernel(int* __restrict__ out, const int* __restrict__ partials, int n) {
  int base = blockIdx.x * 2048 + threadIdx.x * 8;
  int add = partials[blockIdx.x];
#pragma unroll
  for (int i = 0; i < 8; ++i) {
    int idx = base + i;
    if (idx < n) out[idx] += add;
  }
  if (blockIdx.x == 0 && threadIdx.x == 0) out[n] = EE;
}

__global__ void place_kernel(const int* __restrict__ srcv, const int* __restrict__ dstv,
                             const int* __restrict__ et, const int* __restrict__ seg_off,
                             int* __restrict__ cursor, int* __restrict__ sorted_src, int E) {
  int e = blockIdx.x * blockDim.x + threadIdx.x;
  if (e < E) {
    int p = et[e] * NN + dstv[e];
    int slot = seg_off[p] + atomicAdd(&cursor[p], 1);
    sorted_src[slot] = srcv[e];
  }
}

static inline void launch_proj(const float* A, const ushort_t* WT, const float* bias,
                               ushort_t* C, int M, int K, hipStream_t stream) {
  hipLaunchKernelGGL(gemm_proj, dim3((M + 127) / 128), dim3(256), 0, stream,
                     A, WT, bias, C, M, K);
}

extern "C" void kernel_launch(void* const* d_in, const int* in_sizes, int n_in,
                              void* d_out, int out_size, void* d_ws, size_t ws_size,
                              hipStream_t stream) {
  const float* x_user = (const float*)d_in[0];
  const float* x_food = (const float*)d_in[1];
  const float* x_ing  = (const float*)d_in[2];
  const float* x_cat  = (const float*)d_in[3];
  const float* x_hab  = (const float*)d_in[4];
  const int*   eidx   = (const int*)d_in[5];
  const int*   etype  = (const int*)d_in[6];
  const float* Wu = (const float*)d_in[7];
  const float* bu = (const float*)d_in[8];
  const float* Wf = (const float*)d_in[9];
  const float* bfp = (const float*)d_in[10];
  const float* Wi = (const float*)d_in[11];
  const float* bi = (const float*)d_in[12];
  const float* Wc = (const float*)d_in[13];
  const float* bc = (const float*)d_in[14];
  const float* Wh = (const float*)d_in[15];
  const float* bh = (const float*)d_in[16];
  const float* W1    = (const float*)d_in[17];
  const float* root1 = (const float*)d_in[18];
  const float* bias1 = (const float*)d_in[19];
  const float* W2    = (const float*)d_in[20];
  const float* root2 = (const float*)d_in[21];
  const float* bias2 = (const float*)d_in[22];

  const int* src = eidx;
  const int* dst = eidx + EE;

  // ---- workspace layout (~95.3 MB) ----
  char* ws = (char*)d_ws;
  ushort_t* xb   = (ushort_t*)(ws);                      // 40,960,000 B
  ushort_t* xb2  = (ushort_t*)(ws + 40960000);           // 40,960,000 B (conv1 output)
  int* seg_off   = (int*)(ws + 81920000);                // (NRR+1)*4 -> 5,120,064 B
  int* cnt_i     = (int*)(ws + 87040064);                // 5,120,000 B (counts, then cursor)
  int* sorted_src= (int*)(ws + 92160064);                // 2,400,000 B
  int* pA        = (int*)(ws + 94560064);                // 4,096 B
  ushort_t* wbuf = (ushort_t*)(ws + 94564160);           // 753,664 B

  ushort_t* WuT = wbuf;            // 128x256 (plain T)
  ushort_t* WfT = wbuf + 32768;    // 128x128
  ushort_t* WiT = wbuf + 49152;
  ushort_t* WcT = wbuf + 65536;    // 128x64
  ushort_t* WhT = wbuf + 73728;
  ushort_t* r1T = wbuf + 81920;    // swizzled image
  ushort_t* r2T = wbuf + 98304;    // swizzled image
  ushort_t* W1T = wbuf + 114688;   // 8 x swizzled image
  ushort_t* W2T = wbuf + 245760;   // 8 x swizzled image

  float* out = (float*)d_out;

  // ---- weight conversion + transpose/swizzle (single kernel) ----
  WSrcs wsrc;
  wsrc.s[0] = Wu; wsrc.s[1] = Wf; wsrc.s[2] = Wi; wsrc.s[3] = Wc; wsrc.s[4] = Wh;
  wsrc.s[5] = root1; wsrc.s[6] = root2; wsrc.s[7] = W1; wsrc.s[8] = W2;
  hipLaunchKernelGGL(wconv_all_kernel, dim3((WTOT + 255) / 256), dim3(256), 0, stream,
                     wsrc, wbuf);

  // ---- input projections -> xb (bf16 x_all) ----
  launch_proj(x_user, WuT, bu, xb + (size_t)0 * DD,      50000, 256, stream);
  launch_proj(x_food, WfT, bfp, xb + (size_t)50000 * DD, 50000, 128, stream);
  launch_proj(x_ing,  WiT, bi, xb + (size_t)100000 * DD, 50000, 128, stream);
  launch_proj(x_cat,  WcT, bc, xb + (size_t)150000 * DD, 5000,  64,  stream);
  launch_proj(x_hab,  WhT, bh, xb + (size_t)155000 * DD, 5000,  64,  stream);

  // ---- bucket edges by (relation, dst): counts -> exscan -> place ----
  hipMemsetAsync(cnt_i, 0, (size_t)NRR * 4, stream);
  hipLaunchKernelGGL(count_kernel, dim3((EE + 255) / 256), dim3(256), 0, stream,
                     dst, etype, cnt_i, EE);
  {
    int nb = (NRR + 2047) / 2048;
    hipLaunchKernelGGL(scan1_kernel, dim3(nb), dim3(256), 0, stream, cnt_i, seg_off, pA, NRR);
    hipLaunchKernelGGL(scan2_kernel, dim3(1), dim3(256), 0, stream, pA, nb);
    hipLaunchKernelGGL(scan3_kernel, dim3(nb), dim3(256), 0, stream, seg_off, pA, NRR);
  }
  hipMemsetAsync(cnt_i, 0, (size_t)NRR * 4, stream);  // reuse as cursor
  hipLaunchKernelGGL(place_kernel, dim3((EE + 255) / 256), dim3(256), 0, stream,
                     src, dst, etype, seg_off, cnt_i, sorted_src, EE);

  const dim3 convGrid(NN / 128);   // 1250, exact

  // ---- conv1: xb2 = relu(conv(xb)) ----
  hipLaunchKernelGGL((rgcn_conv<true>), convGrid, dim3(512), 0, stream,
                     xb, seg_off, sorted_src, W1T, r1T, bias1, (float*)nullptr, xb2);

  // ---- conv2: d_out = conv(xb2) (f32) ----
  hipLaunchKernelGGL((rgcn_conv<false>), convGrid, dim3(512), 0, stream,
                     xb2, seg_off, sorted_src, W2T, r2T, bias2, out, (ushort_t*)nullptr);
}

// Round 15
// 385.021 us; speedup vs baseline: 1.0557x; 1.0557x over previous
//
#include <hip/hip_runtime.h>

typedef unsigned short ushort_t;
typedef unsigned int uint_t;
typedef __attribute__((ext_vector_type(8))) __bf16 bf16x8;
typedef __attribute__((ext_vector_type(4))) float f32x4;
typedef __attribute__((ext_vector_type(4))) uint_t uint4v;

#define NN 160000
#define DD 128
#define EE 600000
#define RR 8
#define NRR (NN * RR)          // 1,280,000 (rel,dst) pairs
#define WTOT 376832            // total bf16 weight elements

__device__ __forceinline__ ushort_t f2b(float f) {
  uint_t u = __float_as_uint(f);
  u = u + 0x7fffu + ((u >> 16) & 1u);   // round-nearest-even
  return (ushort_t)(u >> 16);
}
__device__ __forceinline__ float b2f(ushort_t u) {
  return __uint_as_float(((uint_t)u) << 16);
}

__device__ __forceinline__ void gload_lds16(const ushort_t* g, ushort_t* l) {
  __builtin_amdgcn_global_load_lds(
      (const __attribute__((address_space(1))) void*)g,
      (__attribute__((address_space(3))) void*)l, 16, 0, 0);
}

// ---------------- merged weight convert+transpose for all 9 matrices ----------------
// m 0..4 (projection weights): plain transposed [128][K].
// m 5..8 (root1, root2, W1, W2): pre-swizzled LDS image: dst[n*128 + ((kc^(n&7))*8 + kr)],
// k = kc*8+kr  — so rgcn_conv can global_load_lds the image linearly.
struct WSrcs { const float* s[9]; };

__global__ void wconv_all_kernel(WSrcs srcs, ushort_t* __restrict__ wbuf) {
  int i = blockIdx.x * blockDim.x + threadIdx.x;
  if (i >= WTOT) return;
  int m, start, K;
  if      (i < 32768)  { m = 0; start = 0;      K = 256; }
  else if (i < 49152)  { m = 1; start = 32768;  K = 128; }
  else if (i < 65536)  { m = 2; start = 49152;  K = 128; }
  else if (i < 73728)  { m = 3; start = 65536;  K = 64;  }
  else if (i < 81920)  { m = 4; start = 73728;  K = 64;  }
  else if (i < 98304)  { m = 5; start = 81920;  K = 128; }
  else if (i < 114688) { m = 6; start = 98304;  K = 128; }
  else if (i < 245760) { m = 7; start = 114688; K = 128; }
  else                 { m = 8; start = 245760; K = 128; }
  int local = i - start;
  int per = K * 128;
  int mat = local / per, rem = local - mat * per;
  int k = rem >> 7, n = rem & 127;
  ushort_t v = f2b(srcs.s[m][local]);
  if (m < 5) {
    wbuf[start + mat * per + n * K + k] = v;
  } else {
    int kc = k >> 3, kr = k & 7;
    int slot = kc ^ (n & 7);
    wbuf[start + mat * per + n * 128 + slot * 8 + kr] = v;
  }
}

// ---------------- projection GEMM: C[M x 128](bf16) = A[M x K](f32) @ WT[128 x K](bf16) ----------------
__global__ __launch_bounds__(256, 2) void gemm_proj(
    const float* __restrict__ Ain, const ushort_t* __restrict__ WT,
    const float* __restrict__ bias, ushort_t* __restrict__ Cout, int M, int K) {
  __shared__ ushort_t As[128 * 128];
  __shared__ ushort_t Ws[128 * 128];
  const int tid = threadIdx.x;
  const int bm = blockIdx.x * 128;
  const int wave = tid >> 6, lane = tid & 63;
  const int lr = lane & 15;
  const int lg = lane >> 4;

  f32x4 acc[2][8];
#pragma unroll
  for (int mt = 0; mt < 2; ++mt)
#pragma unroll
    for (int nt = 0; nt < 8; ++nt) acc[mt][nt] = {0.f, 0.f, 0.f, 0.f};

  for (int k0 = 0; k0 < K; k0 += 128) {
#pragma unroll
    for (int it = 0; it < 8; ++it) {
      int row = it * 16 + (tid >> 4);
      int c = tid & 15;
      uint4v val = {0, 0, 0, 0};
      int grow = bm + row, gk = k0 + c * 8;
      if (grow < M && gk < K) {
        const float* ap = Ain + (size_t)grow * K + gk;
        float4 v0 = *(const float4*)ap;
        float4 v1 = *(const float4*)(ap + 4);
        val[0] = (uint_t)f2b(v0.x) | ((uint_t)f2b(v0.y) << 16);
        val[1] = (uint_t)f2b(v0.z) | ((uint_t)f2b(v0.w) << 16);
        val[2] = (uint_t)f2b(v1.x) | ((uint_t)f2b(v1.y) << 16);
        val[3] = (uint_t)f2b(v1.z) | ((uint_t)f2b(v1.w) << 16);
      }
      *(uint4v*)&As[row * 128 + ((c ^ (row & 7)) * 8)] = val;
    }
#pragma unroll
    for (int it = 0; it < 8; ++it) {
      int n = it * 16 + (tid >> 4);
      int c = tid & 15;
      uint4v val = {0, 0, 0, 0};
      int gk = k0 + c * 8;
      if (gk < K)
        val = *(const uint4v*)(WT + (size_t)n * K + gk);
      *(uint4v*)&Ws[n * 128 + ((c ^ (n & 7)) * 8)] = val;
    }
    __syncthreads();
#pragma unroll
    for (int ks = 0; ks < 4; ++ks) {
      int chunk = ks * 4 + lg;
      bf16x8 af[2], bfr[8];
#pragma unroll
      for (int mt = 0; mt < 2; ++mt) {
        int row = wave * 32 + mt * 16 + lr;
        af[mt] = *(const bf16x8*)&As[row * 128 + ((chunk ^ (row & 7)) * 8)];
      }
#pragma unroll
      for (int nt = 0; nt < 8; ++nt) {
        int n = nt * 16 + lr;
        bfr[nt] = *(const bf16x8*)&Ws[n * 128 + ((chunk ^ (n & 7)) * 8)];
      }
#pragma unroll
      for (int mt = 0; mt < 2; ++mt)
#pragma unroll
        for (int nt = 0; nt < 8; ++nt)
          acc[mt][nt] = __builtin_amdgcn_mfma_f32_16x16x32_bf16(
              af[mt], bfr[nt], acc[mt][nt], 0, 0, 0);
    }
    __syncthreads();
  }

  float bv[8];
#pragma unroll
  for (int nt = 0; nt < 8; ++nt) bv[nt] = bias[nt * 16 + lr];

#pragma unroll
  for (int mt = 0; mt < 2; ++mt) {
    int rbase = bm + wave * 32 + mt * 16 + lg * 4;
#pragma unroll
    for (int i = 0; i < 4; ++i) {
      int row = rbase + i;
      if (row >= M) continue;
#pragma unroll
      for (int nt = 0; nt < 8; ++nt)
        Cout[(size_t)row * 128 + nt * 16 + lr] = f2b(acc[mt][nt][i] + bv[nt]);
    }
  }
}

// ---------------- pipelined fused RGCN conv (r9 structure + predicated gathers + setprio) ----------------
// out[d] = xin[d]@root + bias + sum_r W_r @ mean_{(r,d)-edges}(xin[src])
// Phases: rels 0..7, then root. Pipeline: bounds 3 ahead, srcs 2 ahead, row-vals 1 ahead.
// barrier2 is lgkm-only (raw s_barrier) so in-flight row gathers survive across it.
template <bool RELU_BF>
__global__ __launch_bounds__(256, 3) void rgcn_conv(
    const ushort_t* __restrict__ xin, const int* __restrict__ seg_off,
    const int* __restrict__ sorted_src,
    const ushort_t* __restrict__ WrT,     // 8 x swizzled 128x128 image
    const ushort_t* __restrict__ rootT,   // swizzled 128x128 image
    const float* __restrict__ bias,
    float* __restrict__ fout, ushort_t* __restrict__ bfout) {
  __shared__ ushort_t As[64 * 128];    // 16 KB
  __shared__ ushort_t Ws[128 * 128];   // 32 KB
  const int tid = threadIdx.x;
  const int bm = blockIdx.x * 64;
  const int wave = tid >> 6, lane = tid & 63;
  const int lr = lane & 15, lg = lane >> 4;
  const int grp = tid >> 4;    // 0..15
  const int sl = tid & 15;

  f32x4 acc[8];
#pragma unroll
  for (int nt = 0; nt < 8; ++nt) acc[nt] = {0.f, 0.f, 0.f, 0.f};

  // pipeline state (fully unrolled loop -> registers, windowed liveness)
  int gsv[8][4], gev[8][4];
  int s0v[8][4], s1v[8][4];
  uint4v f0v[8][4], f1v[8][4];
  uint4v rootv[4];

#define BOUNDS(P)                                                         \
  {                                                                       \
    _Pragma("unroll") for (int q = 0; q < 4; ++q) {                       \
      int g = (P) * NN + bm + q * 16 + grp;                               \
      gsv[P][q] = seg_off[g];                                             \
      gev[P][q] = seg_off[g + 1];                                         \
    }                                                                     \
  }

// unconditional clamped (branch-free, batched) index loads — cheap, sequential
#define SRCS(P)                                                           \
  {                                                                       \
    _Pragma("unroll") for (int q = 0; q < 4; ++q) {                       \
      int a = gsv[P][q];                                                  \
      int c = gev[P][q] - a;                                              \
      int i0 = (a < EE - 1) ? a : (EE - 1);                               \
      int i1 = (c > 1) ? (a + 1) : i0;                                    \
      s0v[P][q] = sorted_src[i0];                                         \
      s1v[P][q] = sorted_src[i1];                                         \
    }                                                                     \
  }

// PREDICATED row-value gathers: only fetch rows that are actually used.
// (unconditional version demanded ~655 MB/conv of L2/L3 reads; only ~23% is used)
#define FVLOAD(P)                                                         \
  {                                                                       \
    _Pragma("unroll") for (int q = 0; q < 4; ++q) {                       \
      int c = gev[P][q] - gsv[P][q];                                      \
      if (c > 0)                                                          \
        f0v[P][q] = *(const uint4v*)(xin + (size_t)s0v[P][q] * DD + sl * 8); \
      if (c > 1)                                                          \
        f1v[P][q] = *(const uint4v*)(xin + (size_t)s1v[P][q] * DD + sl * 8); \
    }                                                                     \
  }

#define GLLW(SRC)                                                         \
  {                                                                       \
    const ushort_t* wsrc = (SRC) + (size_t)wave * 4096 + lane * 8;        \
    _Pragma("unroll") for (int i = 0; i < 8; ++i)                         \
      gload_lds16(wsrc + i * 512, &Ws[wave * 4096 + i * 512]);            \
  }

  // ---- prologue ----
  BOUNDS(0); BOUNDS(1); BOUNDS(2);
  GLLW(WrT);
  SRCS(0); SRCS(1);
  FVLOAD(0);
  __builtin_amdgcn_sched_barrier(0);

#pragma unroll
  for (int p = 0; p < 8; ++p) {
    // ---- A-write: means for rel p (consumes f0/f1[p]) ----
#pragma unroll
    for (int q = 0; q < 4; ++q) {
      int row = q * 16 + grp;
      int a = gsv[p][q];
      int c = gev[p][q] - a;
      uint4v o = {0, 0, 0, 0};
      if (c == 1) {
        o = f0v[p][q];                  // mean of one = itself (bit-exact)
      } else if (c == 2) {
        uint4v x0 = f0v[p][q], x1 = f1v[p][q];
#pragma unroll
        for (int j = 0; j < 4; ++j) {
          float e0 = (b2f((ushort_t)(x0[j] & 0xffff)) + b2f((ushort_t)(x1[j] & 0xffff))) * 0.5f;
          float e1 = (b2f((ushort_t)(x0[j] >> 16)) + b2f((ushort_t)(x1[j] >> 16))) * 0.5f;
          o[j] = (uint_t)f2b(e0) | ((uint_t)f2b(e1) << 16);
        }
      } else if (c >= 3) {
        uint4v x0 = f0v[p][q], x1 = f1v[p][q];
        float av[8];
#pragma unroll
        for (int j = 0; j < 4; ++j) {
          av[j * 2]     = b2f((ushort_t)(x0[j] & 0xffff)) + b2f((ushort_t)(x1[j] & 0xffff));
          av[j * 2 + 1] = b2f((ushort_t)(x0[j] >> 16)) + b2f((ushort_t)(x1[j] >> 16));
        }
        for (int i = a + 2; i < a + c; ++i) {
          int s = sorted_src[i];
          uint4v v2 = *(const uint4v*)(xin + (size_t)s * DD + sl * 8);
#pragma unroll
          for (int j = 0; j < 4; ++j) {
            av[j * 2]     += b2f((ushort_t)(v2[j] & 0xffff));
            av[j * 2 + 1] += b2f((ushort_t)(v2[j] >> 16));
          }
        }
        float sc = 1.0f / (float)c;
#pragma unroll
        for (int j = 0; j < 4; ++j)
          o[j] = (uint_t)f2b(av[j * 2] * sc) | ((uint_t)f2b(av[j * 2 + 1] * sc) << 16);
      }
      *(uint4v*)&As[row * 128 + ((sl ^ (row & 7)) * 8)] = o;
    }

    __syncthreads();   // barrier1: A_p + W_p (gll) visible

    // ---- issue next phase's row-value gathers (survive barrier2) ----
    if (p < 7) {
      FVLOAD(p + 1);
    } else {
#pragma unroll
      for (int q = 0; q < 4; ++q)
        rootv[q] = *(const uint4v*)(xin + (size_t)(bm + q * 16 + grp) * DD + sl * 8);
    }
    __builtin_amdgcn_sched_barrier(0);

    // ---- MFMA accumulate for phase p ----
    __builtin_amdgcn_s_setprio(1);
#pragma unroll
    for (int ks = 0; ks < 4; ++ks) {
      int chunk = ks * 4 + lg;
      int arow = wave * 16 + lr;
      bf16x8 af = *(const bf16x8*)&As[arow * 128 + ((chunk ^ (arow & 7)) * 8)];
      bf16x8 bfr[8];
#pragma unroll
      for (int nt = 0; nt < 8; ++nt) {
        int n = nt * 16 + lr;
        bfr[nt] = *(const bf16x8*)&Ws[n * 128 + ((chunk ^ (n & 7)) * 8)];
      }
#pragma unroll
      for (int nt = 0; nt < 8; ++nt)
        acc[nt] = __builtin_amdgcn_mfma_f32_16x16x32_bf16(af, bfr[nt], acc[nt], 0, 0, 0);
    }
    __builtin_amdgcn_s_setprio(0);

    // barrier2: lgkm-only (LDS reads done) — does NOT drain the fv gathers
    asm volatile("s_waitcnt lgkmcnt(0)" ::: "memory");
    __builtin_amdgcn_s_barrier();
    __builtin_amdgcn_sched_barrier(0);

    // ---- refill W for next phase; extend index pipeline ----
    if (p < 7) {
      GLLW(WrT + (size_t)(p + 1) * 16384);
    } else {
      GLLW(rootT);
    }
    if (p < 6) { SRCS(p + 2); }
    if (p < 5) { BOUNDS(p + 3); }
    __builtin_amdgcn_sched_barrier(0);
  }

  // ---- phase 8: root ----
#pragma unroll
  for (int q = 0; q < 4; ++q) {
    int row = q * 16 + grp;
    *(uint4v*)&As[row * 128 + ((sl ^ (row & 7)) * 8)] = rootv[q];
  }
  __syncthreads();   // drains root-W gll, A visible
  __builtin_amdgcn_s_setprio(1);
#pragma unroll
  for (int ks = 0; ks < 4; ++ks) {
    int chunk = ks * 4 + lg;
    int arow = wave * 16 + lr;
    bf16x8 af = *(const bf16x8*)&As[arow * 128 + ((chunk ^ (arow & 7)) * 8)];
    bf16x8 bfr[8];
#pragma unroll
    for (int nt = 0; nt < 8; ++nt) {
      int n = nt * 16 + lr;
      bfr[nt] = *(const bf16x8*)&Ws[n * 128 + ((chunk ^ (n & 7)) * 8)];
    }
#pragma unroll
    for (int nt = 0; nt < 8; ++nt)
      acc[nt] = __builtin_amdgcn_mfma_f32_16x16x32_bf16(af, bfr[nt], acc[nt], 0, 0, 0);
  }
  __builtin_amdgcn_s_setprio(0);

  // ---- epilogue: bias (+relu) and write ----
  float bv[8];
#pragma unroll
  for (int nt = 0; nt < 8; ++nt) bv[nt] = bias[nt * 16 + lr];

  int rbase = bm + wave * 16 + lg * 4;
#pragma unroll
  for (int i = 0; i < 4; ++i) {
    int row = rbase + i;
#pragma unroll
    for (int nt = 0; nt < 8; ++nt) {
      float v = acc[nt][i] + bv[nt];
      if (RELU_BF)
        bfout[(size_t)row * 128 + nt * 16 + lr] = f2b(fmaxf(v, 0.f));
      else
        fout[(size_t)row * 128 + nt * 16 + lr] = v;
    }
  }
#undef BOUNDS
#undef SRCS
#undef FVLOAD
#undef GLLW
}

// ---------------- edge bucketing ----------------
__global__ void count_kernel(const int* __restrict__ dstv, const int* __restrict__ et,
                             int* __restrict__ cnt, int E) {
  int e = blockIdx.x * blockDim.x + threadIdx.x;
  if (e < E) atomicAdd(&cnt[(size_t)et[e] * NN + dstv[e]], 1);
}

__global__ __launch_bounds__(256) void scan1_kernel(const int* __restrict__ in, int* __restrict__ out,
                                                    int* __restrict__ partials, int n) {
  __shared__ int sums[256];
  int tid = threadIdx.x;
  int base = blockIdx.x * 2048 + tid * 8;
  int v[8];
  int s = 0;
#pragma unroll
  for (int i = 0; i < 8; ++i) {
    int idx = base + i;
    int x = (idx < n) ? in[idx] : 0;
    v[i] = s;
    s += x;
  }
  sums[tid] = s;
  __syncthreads();
  for (int off = 1; off < 256; off <<= 1) {
    int t = (tid >= off) ? sums[tid - off] : 0;
    __syncthreads();
    sums[tid] += t;
    __syncthreads();
  }
  int excl = (tid == 0) ? 0 : sums[tid - 1];
  if (tid == 255) partials[blockIdx.x] = sums[255];
#pragma unroll
  for (int i = 0; i < 8; ++i) {
    int idx = base + i;
    if (idx < n) out[idx] = excl + v[i];
  }
}

__global__ __launch_bounds__(256) void scan2_kernel(int* __restrict__ partials, int nb) {
  __shared__ int sums[256];
  int tid = threadIdx.x;
  int per = (nb + 255) / 256;
  int start = tid * per;
  int s = 0;
  for (int i = 0; i < per; ++i) {
    int idx = start + i;
    if (idx < nb) s += partials[idx];
  }
  sums[tid] = s;
  __syncthreads();
  for (int off = 1; off < 256; off <<= 1) {
    int t = (tid >= off) ? sums[tid - off] : 0;
    __syncthreads();
    sums[tid] += t;
    __syncthreads();
  }
  int excl = (tid == 0) ? 0 : sums[tid - 1];
  for (int i = 0; i < per; ++i) {
    int idx = start + i;
    if (idx < nb) {
      int t = partials[idx];
      partials[idx] = excl;
      excl += t;
    }
  }
}

// also writes the sentinel out[n] = EE (out must have n+1 slots)
__global__ void scan3_kernel(int* __restrict__ out, const int* __restrict__ partials, int n) {
  int base = blockIdx.x * 2048 + threadIdx.x * 8;
  int add = partials[blockIdx.x];
#pragma unroll
  for (int i = 0; i < 8; ++i) {
    int idx = base + i;
    if (idx < n) out[idx] += add;
  }
  if (blockIdx.x == 0 && threadIdx.x == 0) out[n] = EE;
}

__global__ void place_kernel(const int* __restrict__ srcv, const int* __restrict__ dstv,
                             const int* __restrict__ et, const int* __restrict__ seg_off,
                             int* __restrict__ cursor, int* __restrict__ sorted_src, int E) {
  int e = blockIdx.x * blockDim.x + threadIdx.x;
  if (e < E) {
    int p = et[e] * NN + dstv[e];
    int slot = seg_off[p] + atomicAdd(&cursor[p], 1);
    sorted_src[slot] = srcv[e];
  }
}

static inline void launch_proj(const float* A, const ushort_t* WT, const float* bias,
                               ushort_t* C, int M, int K, hipStream_t stream) {
  hipLaunchKernelGGL(gemm_proj, dim3((M + 127) / 128), dim3(256), 0, stream,
                     A, WT, bias, C, M, K);
}

extern "C" void kernel_launch(void* const* d_in, const int* in_sizes, int n_in,
                              void* d_out, int out_size, void* d_ws, size_t ws_size,
                              hipStream_t stream) {
  const float* x_user = (const float*)d_in[0];
  const float* x_food = (const float*)d_in[1];
  const float* x_ing  = (const float*)d_in[2];
  const float* x_cat  = (const float*)d_in[3];
  const float* x_hab  = (const float*)d_in[4];
  const int*   eidx   = (const int*)d_in[5];
  const int*   etype  = (const int*)d_in[6];
  const float* Wu = (const float*)d_in[7];
  const float* bu = (const float*)d_in[8];
  const float* Wf = (const float*)d_in[9];
  const float* bfp = (const float*)d_in[10];
  const float* Wi = (const float*)d_in[11];
  const float* bi = (const float*)d_in[12];
  const float* Wc = (const float*)d_in[13];
  const float* bc = (const float*)d_in[14];
  const float* Wh = (const float*)d_in[15];
  const float* bh = (const float*)d_in[16];
  const float* W1    = (const float*)d_in[17];
  const float* root1 = (const float*)d_in[18];
  const float* bias1 = (const float*)d_in[19];
  const float* W2    = (const float*)d_in[20];
  const float* root2 = (const float*)d_in[21];
  const float* bias2 = (const float*)d_in[22];

  const int* src = eidx;
  const int* dst = eidx + EE;

  // ---- workspace layout (~95.3 MB) ----
  char* ws = (char*)d_ws;
  ushort_t* xb   = (ushort_t*)(ws);                      // 40,960,000 B
  ushort_t* xb2  = (ushort_t*)(ws + 40960000);           // 40,960,000 B (conv1 output)
  int* seg_off   = (int*)(ws + 81920000);                // (NRR+1)*4 -> 5,120,064 B
  int* cnt_i     = (int*)(ws + 87040064);                // 5,120,000 B (counts, then cursor)
  int* sorted_src= (int*)(ws + 92160064);                // 2,400,000 B
  int* pA        = (int*)(ws + 94560064);                // 4,096 B
  ushort_t* wbuf = (ushort_t*)(ws + 94564160);           // 753,664 B

  ushort_t* WuT = wbuf;            // 128x256 (plain T)
  ushort_t* WfT = wbuf + 32768;    // 128x128
  ushort_t* WiT = wbuf + 49152;
  ushort_t* WcT = wbuf + 65536;    // 128x64
  ushort_t* WhT = wbuf + 73728;
  ushort_t* r1T = wbuf + 81920;    // swizzled image
  ushort_t* r2T = wbuf + 98304;    // swizzled image
  ushort_t* W1T = wbuf + 114688;   // 8 x swizzled image
  ushort_t* W2T = wbuf + 245760;   // 8 x swizzled image

  float* out = (float*)d_out;

  // ---- weight conversion + transpose/swizzle (single kernel) ----
  WSrcs wsrc;
  wsrc.s[0] = Wu; wsrc.s[1] = Wf; wsrc.s[2] = Wi; wsrc.s[3] = Wc; wsrc.s[4] = Wh;
  wsrc.s[5] = root1; wsrc.s[6] = root2; wsrc.s[7] = W1; wsrc.s[8] = W2;
  hipLaunchKernelGGL(wconv_all_kernel, dim3((WTOT + 255) / 256), dim3(256), 0, stream,
                     wsrc, wbuf);

  // ---- input projections -> xb (bf16 x_all) ----
  launch_proj(x_user, WuT, bu, xb + (size_t)0 * DD,      50000, 256, stream);
  launch_proj(x_food, WfT, bfp, xb + (size_t)50000 * DD, 50000, 128, stream);
  launch_proj(x_ing,  WiT, bi, xb + (size_t)100000 * DD, 50000, 128, stream);
  launch_proj(x_cat,  WcT, bc, xb + (size_t)150000 * DD, 5000,  64,  stream);
  launch_proj(x_hab,  WhT, bh, xb + (size_t)155000 * DD, 5000,  64,  stream);

  // ---- bucket edges by (relation, dst): counts -> exscan -> place ----
  hipMemsetAsync(cnt_i, 0, (size_t)NRR * 4, stream);
  hipLaunchKernelGGL(count_kernel, dim3((EE + 255) / 256), dim3(256), 0, stream,
                     dst, etype, cnt_i, EE);
  {
    int nb = (NRR + 2047) / 2048;
    hipLaunchKernelGGL(scan1_kernel, dim3(nb), dim3(256), 0, stream, cnt_i, seg_off, pA, NRR);
    hipLaunchKernelGGL(scan2_kernel, dim3(1), dim3(256), 0, stream, pA, nb);
    hipLaunchKernelGGL(scan3_kernel, dim3(nb), dim3(256), 0, stream, seg_off, pA, NRR);
  }
  hipMemsetAsync(cnt_i, 0, (size_t)NRR * 4, stream);  // reuse as cursor
  hipLaunchKernelGGL(place_kernel, dim3((EE + 255) / 256), dim3(256), 0, stream,
                     src, dst, etype, seg_off, cnt_i, sorted_src, EE);

  const dim3 convGrid(NN / 64);    // 2500, exact

  // ---- conv1: xb2 = relu(conv(xb)) ----
  hipLaunchKernelGGL((rgcn_conv<true>), convGrid, dim3(256), 0, stream,
                     xb, seg_off, sorted_src, W1T, r1T, bias1, (float*)nullptr, xb2);

  // ---- conv2: d_out = conv(xb2) (f32) ----
  hipLaunchKernelGGL((rgcn_conv<false>), convGrid, dim3(256), 0, stream,
                     xb2, seg_off, sorted_src, W2T, r2T, bias2, out, (ushort_t*)nullptr);
}